// Round 12
// baseline (693.354 us; speedup 1.0000x reference)
//
#include <hip/hip_runtime.h>

// LIF scan: B=16, S=256, H=128, N=64. T = S*H = 32768 sequential steps per
// (b,n) chain; 1024 chains. Bit-exactness with the fp32 sequential reference
// required -> add chain cannot be reassociated. Chain form (proven bit-exact
// R6..R18):   s' = prev ? x : fl(s + x);  prev' = s' > th
//
// R19: R18 (vcc asm chain) = 224us = 16.4 cyc/step; H2 confirmed (336->224).
// Cycle has 2 dep edges; issue floor is 6 cyc/step -> ~10 cyc/step is dep
// latency + the VALU-writes-VCC -> VALU-reads-VCC hazard, which a LONE wave
// cannot fill. Fix: interleave TWO batches' chains per wave (th is common:
// same lane->neuron map). Chain A mask in vcc (R18-proven); chain B mask in
// literal s[20:21] within each asm block (clobbered), carried across blocks
// as a 0/1 VGPR. 6 instr/round, both chains advance per round -> wall ~
// 32768 x ~14 cyc ~ 190us, 8 blocks. If chain stays >=215us, 16.4 cyc/step
// is a latency floor -> structural ceiling, declare next round.
//
// Pass2: BYTE-IDENTICAL to R8..R18 (proven absmax=0 seven times).

namespace {
constexpr int kB = 16;
constexpr int kS = 256;
constexpr int kH = 128;
constexpr int kN = 64;
constexpr int kT = kS * kH;                 // 32768
constexpr long kPerB = (long)kS * kN * kH;  // 2,097,152 per batch per tensor
// ws layout: ckpt_s | ckpt_m
constexpr size_t kWsS = (size_t)kB * kS * kN * sizeof(float);          // 1 MB
constexpr size_t kWsM = (size_t)kB * kS * sizeof(unsigned long long);  // 32 KB
}

typedef float v4f __attribute__((ext_vector_type(4)));
typedef unsigned long long u64;

// Opaque VGPR zero: defeats uniform-scalarization so wave-uniform-looking
// loads use the vector path (vmcnt, in-order) instead of SMEM s_loads
// (lgkmcnt, unordered -> full drains). Proven effective in R6.
__device__ __forceinline__ int opaque_vgpr_zero() {
  int z;
  asm volatile("v_mov_b32 %0, 0" : "=v"(z));
  return z;
}

// One interleaved round: chain A (mask=vcc) + chain B (mask=s[20:21]).
// cndmask consumes the PREVIOUS round's mask; cmp overwrites for the next.
// A's vcc write->read gap = 4 instrs (hazard absorbed by B's instructions).
#define LIF_STEP2(XA, XB)                                 \
  "v_add_f32 %[tA], %[sA], %[" XA "]\n\t"                 \
  "v_add_f32 %[tB], %[sB], %[" XB "]\n\t"                 \
  "v_cndmask_b32 %[sA], %[tA], %[" XA "], vcc\n\t"        \
  "v_cndmask_b32 %[sB], %[tB], %[" XB "], s[20:21]\n\t"   \
  "v_cmp_gt_f32 vcc, %[sA], %[th]\n\t"                    \
  "v_cmp_gt_f32 s[20:21], %[sB], %[th]\n\t"

// 8 steps of both chains in one asm block (23 operands). pvA/pvB: 0/1 int
// VGPRs carrying prev across blocks; vcc/s[20:21] live only inside.
#define CHAIN8X2(QA0, QA1, QB0, QB1)                                        \
  {                                                                         \
    float tA_, tB_;                                                         \
    asm volatile(                                                           \
        "v_cmp_ne_u32 vcc, 0, %[pvA]\n\t"                                   \
        "v_cmp_ne_u32 s[20:21], 0, %[pvB]\n\t"                              \
        LIF_STEP2("a0", "b0") LIF_STEP2("a1", "b1")                         \
        LIF_STEP2("a2", "b2") LIF_STEP2("a3", "b3")                         \
        LIF_STEP2("a4", "b4") LIF_STEP2("a5", "b5")                         \
        LIF_STEP2("a6", "b6") LIF_STEP2("a7", "b7")                         \
        "v_cndmask_b32 %[pvA], 0, 1, vcc\n\t"                               \
        "v_cndmask_b32 %[pvB], 0, 1, s[20:21]\n\t"                          \
        : [sA] "+v"(sA), [sB] "+v"(sB), [pvA] "+v"(pvA), [pvB] "+v"(pvB),   \
          [tA] "=&v"(tA_), [tB] "=&v"(tB_)                                  \
        : [a0] "v"((QA0)[0]), [a1] "v"((QA0)[1]), [a2] "v"((QA0)[2]),       \
          [a3] "v"((QA0)[3]), [a4] "v"((QA1)[0]), [a5] "v"((QA1)[1]),       \
          [a6] "v"((QA1)[2]), [a7] "v"((QA1)[3]), [b0] "v"((QB0)[0]),       \
          [b1] "v"((QB0)[1]), [b2] "v"((QB0)[2]), [b3] "v"((QB0)[3]),       \
          [b4] "v"((QB1)[0]), [b5] "v"((QB1)[1]), [b6] "v"((QB1)[2]),       \
          [b7] "v"((QB1)[3]), [th] "v"(th)                                  \
        : "vcc", "s20", "s21");                                             \
  }

// ---------------------------------------------------------------------------
// K1: the sequential chains, exact, two batches per wave. 8 blocks x 64
// threads; block bid owns batches 2*bid, 2*bid+1. x staged into LDS in 32KB
// quarters per batch (64KB total); 4-buffer rotation per batch +
// sched_barrier(0) fences (R16/R18 structure); interleaved asm chain.
// Checkpoints (entering state + ballot(prev)) at every row for both batches.
// ---------------------------------------------------------------------------
__global__ __launch_bounds__(64, 1) void lif_chain2_kernel(
    const float* __restrict__ x, const float* __restrict__ thresh,
    const float* __restrict__ acc0, float* __restrict__ ckpt_s,
    u64* __restrict__ ckpt_m) {
  const int bid = blockIdx.x;
  const int b0 = 2 * bid;
  const int b1 = 2 * bid + 1;
  const int lane = threadIdx.x;
  const float th = thresh[lane];

  __shared__ v4f xs2[2][2048];  // 64 KB: one quarter of each batch

  const v4f* __restrict__ xg0 =
      (const v4f*)(x + (long)b0 * kT) + opaque_vgpr_zero();
  const v4f* __restrict__ xg1 =
      (const v4f*)(x + (long)b1 * kT) + opaque_vgpr_zero();

  float sA = acc0[b0 * kN + lane];
  float sB = acc0[b1 * kN + lane];
  int pvA = 0, pvB = 0;  // prev as 0/1 (false at t=0)

  float* __restrict__ csA = ckpt_s + (long)b0 * kS * kN + lane;
  float* __restrict__ csB = ckpt_s + (long)b1 * kS * kN + lane;
  u64* __restrict__ cmA = ckpt_m + (long)b0 * kS;
  u64* __restrict__ cmB = ckpt_m + (long)b1 * kS;

#pragma unroll 1
  for (int q = 0; q < 4; ++q) {
    // ---- stage quarter q for both batches (proven pattern, sequential per
    // batch to bound transient VGPRs; single wave -> DS in-order, no barrier)
    {
      const v4f* __restrict__ src0 = xg0 + (long)q * 2048 + lane;
      v4f tmp[32];
#pragma unroll
      for (int i = 0; i < 32; ++i) tmp[i] = src0[i * 64];
#pragma unroll
      for (int i = 0; i < 32; ++i) xs2[0][i * 64 + lane] = tmp[i];
    }
    {
      const v4f* __restrict__ src1 = xg1 + (long)q * 2048 + lane;
      v4f tmp[32];
#pragma unroll
      for (int i = 0; i < 32; ++i) tmp[i] = src1[i * 64];
#pragma unroll
      for (int i = 0; i < 32; ++i) xs2[1][i * 64 + lane] = tmp[i];
    }

    const v4f* __restrict__ xs0 = xs2[0];
    const v4f* __restrict__ xs1 = xs2[1];

    // ---- consume: 512 flat groups/batch (64 rows x 8 groups of 16 steps).
    // Per batch a 4-set rotation (A..D / E..H): group k consumes set (k%4),
    // prefetches flat-group gq+2 into set ((k+2)%4).
    v4f A0, A1, A2, A3, B0, B1, B2, B3;
    v4f C0, C1, C2, C3, D0, D1, D2, D3;
    v4f E0, E1, E2, E3, F0, F1, F2, F3;
    v4f G0, G1, G2, G3, H0, H1, H2, H3;
    A0 = xs0[0]; A1 = xs0[1]; A2 = xs0[2]; A3 = xs0[3];
    B0 = xs0[4]; B1 = xs0[5]; B2 = xs0[6]; B3 = xs0[7];
    E0 = xs1[0]; E1 = xs1[1]; E2 = xs1[2]; E3 = xs1[3];
    F0 = xs1[4]; F1 = xs1[5]; F2 = xs1[6]; F3 = xs1[7];
    __builtin_amdgcn_sched_barrier(0);

#define LIF_GROUP2(U0, U1, U2, U3, P0, P1, P2, P3, V0, V1, V2, V3, Q0, Q1, \
                   Q2, Q3, OFS)                                            \
  {                                                                        \
    const int pf = (gq + (OFS) <= 511) ? (gq + (OFS)) : 511;               \
    P0 = xs0[4 * pf + 0];                                                  \
    P1 = xs0[4 * pf + 1];                                                  \
    P2 = xs0[4 * pf + 2];                                                  \
    P3 = xs0[4 * pf + 3];                                                  \
    Q0 = xs1[4 * pf + 0];                                                  \
    Q1 = xs1[4 * pf + 1];                                                  \
    Q2 = xs1[4 * pf + 2];                                                  \
    Q3 = xs1[4 * pf + 3];                                                  \
    __builtin_amdgcn_sched_barrier(0);                                     \
    CHAIN8X2(U0, U1, V0, V1)                                               \
    CHAIN8X2(U2, U3, V2, V3)                                               \
    __builtin_amdgcn_sched_barrier(0);                                     \
  }

#pragma unroll 1
    for (int j = 0; j < 64; ++j) {
      const int r = q * 64 + j;
      // checkpoints: entering state, both batches
      csA[(long)r * kN] = sA;
      csB[(long)r * kN] = sB;
      {
        const u64 mA = __ballot(pvA != 0);
        const u64 mB = __ballot(pvB != 0);
        if (lane == 0) {
          cmA[r] = mA;
          cmB[r] = mB;
        }
      }
      const int gq = j * 8;
      LIF_GROUP2(A0, A1, A2, A3, C0, C1, C2, C3, E0, E1, E2, E3, G0, G1, G2,
                 G3, 2)
      LIF_GROUP2(B0, B1, B2, B3, D0, D1, D2, D3, F0, F1, F2, F3, H0, H1, H2,
                 H3, 3)
      LIF_GROUP2(C0, C1, C2, C3, A0, A1, A2, A3, G0, G1, G2, G3, E0, E1, E2,
                 E3, 4)
      LIF_GROUP2(D0, D1, D2, D3, B0, B1, B2, B3, H0, H1, H2, H3, F0, F1, F2,
                 F3, 5)
      LIF_GROUP2(A0, A1, A2, A3, C0, C1, C2, C3, E0, E1, E2, E3, G0, G1, G2,
                 G3, 6)
      LIF_GROUP2(B0, B1, B2, B3, D0, D1, D2, D3, F0, F1, F2, F3, H0, H1, H2,
                 H3, 7)
      LIF_GROUP2(C0, C1, C2, C3, A0, A1, A2, A3, G0, G1, G2, G3, E0, E1, E2,
                 E3, 8)
      LIF_GROUP2(D0, D1, D2, D3, B0, B1, B2, B3, H0, H1, H2, H3, F0, F1, F2,
                 F3, 9)
    }
#undef LIF_GROUP2
    // invariant: sets A/B (E/F) hold stale next-quarter data; prologue
    // reloads after restaging. DS pipe in-order per wave.
  }
}

// ---------------------------------------------------------------------------
// K2: replay + dense coalesced write (byte-identical to R8..R18 pass2,
// proven absmax = 0). One wave per (b,row); lane = n.
// ---------------------------------------------------------------------------
__global__ __launch_bounds__(64, 2) void lif_pass2_kernel(
    const float* __restrict__ x, const float* __restrict__ thresh,
    const float* __restrict__ ckpt_s, const u64* __restrict__ ckpt_m,
    float* __restrict__ out) {
  const int wid = blockIdx.x;
  const int b = wid >> 8;
  const int srow = wid & 255;
  const int lane = threadIdx.x;

  __shared__ float ov[kH / 2][kN + 1];  // 16.6 KB

  const v4f* __restrict__ xr4 =
      (const v4f*)(x + (long)b * kT + srow * kH) + opaque_vgpr_zero();

  v4f xb[32];
#pragma unroll
  for (int i = 0; i < 32; ++i) xb[i] = xr4[i];  // 32 loads in flight

  const float th = thresh[lane];
  float s = ckpt_s[((long)b * kS + srow) * kN + lane];
  bool prev = (ckpt_m[b * kS + srow] >> lane) & 1ULL;

  float* __restrict__ obase = out + (long)b * kPerB + (long)srow * (kN * kH);
  float* __restrict__ sbase = obase + (long)kB * kPerB;

#pragma unroll
  for (int half = 0; half < 2; ++half) {
#pragma unroll
    for (int hh = 0; hh < kH / 2; ++hh) {
      const int h = half * (kH / 2) + hh;
      const float xt = xb[h >> 2][h & 3];
      const float u = s + xt;
      s = prev ? xt : u;  // bit-identical replay
      prev = s > th;
      ov[hh][lane] = prev ? s : 0.0f;
    }
    const int q = lane & 15;
    const int nsub = lane >> 4;
    const int h0 = half * (kH / 2) + q * 4;
#pragma unroll
    for (int i = 0; i < 16; ++i) {
      const int n = i * 4 + nsub;
      v4f o, sp;
#pragma unroll
      for (int j = 0; j < 4; ++j) {
        const float v = ov[q * 4 + j][n];
        o[j] = v;
        sp[j] = v > 0.0f ? 1.0f : 0.0f;
      }
      *(v4f*)(obase + (long)n * kH + h0) = o;
      *(v4f*)(sbase + (long)n * kH + h0) = sp;
    }
  }
}

// ---------------------------------------------------------------------------
// Fallback (tiny ws): R4's passing fused kernel (unchanged).
// ---------------------------------------------------------------------------
__global__ __launch_bounds__(128) void lif_fused_kernel(
    const float* __restrict__ x, const float* __restrict__ thresh,
    const float* __restrict__ acc0, float* __restrict__ out) {
  const int bid = blockIdx.x;
  const int b = bid >> 2;
  const int ng = bid & 3;
  const int tid = threadIdx.x;
  const int wave = tid >> 6;
  const int lane = tid & 63;
  __shared__ float buf[2][kH][64];
  const float* __restrict__ xb = x + (long)b * kT;
  float* __restrict__ outs_g = out + (long)b * kPerB + (long)(ng * 16) * kH;
  float* __restrict__ spks_g = outs_g + (long)kB * kPerB;
  if (wave == 0) {
    const int n = lane & 15;
    const float th = thresh[ng * 16 + n];
    float s = acc0[b * kN + ng * 16 + n];
    bool prev = false;
    for (int r = 0; r < kS + 1; ++r) {
      if (r < kS) {
        float* __restrict__ bk = &buf[r & 1][0][lane];
        const float* __restrict__ xr = xb + r * kH;
#pragma unroll
        for (int k = 0; k < kH; ++k) {
          const float xt = xr[k];
          const float u = s + xt;
          s = prev ? xt : u;
          prev = s > th;
          bk[k * 64] = s;
        }
      }
      __syncthreads();
    }
  } else {
    const int n = lane >> 2;
    const int hg = lane & 3;
    const float th = thresh[ng * 16 + n];
    for (int r = 0; r < kS + 1; ++r) {
      if (r > 0) {
        const int rr = r - 1;
        const float(*bk)[64] = buf[rr & 1];
        float* __restrict__ orow = outs_g + (long)rr * (kN * kH) + n * kH;
        float* __restrict__ srow = spks_g + (long)rr * (kN * kH) + n * kH;
#pragma unroll
        for (int i = 0; i < 8; ++i) {
          const int hh = hg * 4 + i * 16;
          v4f ovv, sv;
#pragma unroll
          for (int j = 0; j < 4; ++j) {
            const float v = bk[hh + j][n];
            const bool sp = v > th;
            ovv[j] = sp ? v : 0.0f;
            sv[j] = sp ? 1.0f : 0.0f;
          }
          *(v4f*)(orow + hh) = ovv;
          *(v4f*)(srow + hh) = sv;
        }
      }
      __syncthreads();
    }
  }
}

// ---------------------------------------------------------------------------
extern "C" void kernel_launch(void* const* d_in, const int* in_sizes, int n_in,
                              void* d_out, int out_size, void* d_ws, size_t ws_size,
                              hipStream_t stream) {
  const float* inputs = (const float*)d_in[0];    // [B,S,H] fp32
  const float* threshes = (const float*)d_in[1];  // [N] fp32
  const float* acc0 = (const float*)d_in[2];      // [B,N] fp32
  float* out = (float*)d_out;

  if (ws_size >= kWsS + kWsM) {
    float* ckpt_s = (float*)d_ws;
    u64* ckpt_m = (u64*)((char*)d_ws + kWsS);
    lif_chain2_kernel<<<kB / 2, kN, 0, stream>>>(inputs, threshes, acc0,
                                                 ckpt_s, ckpt_m);
    lif_pass2_kernel<<<kB * kS, kN, 0, stream>>>(inputs, threshes, ckpt_s,
                                                 ckpt_m, out);
  } else {
    lif_fused_kernel<<<kB * 4, 128, 0, stream>>>(inputs, threshes, acc0, out);
  }
}

// Round 14
// 519.970 us; speedup vs baseline: 1.3334x; 1.3334x over previous
//
#include <hip/hip_runtime.h>

// LIF scan: B=16, S=256, H=128, N=64. T = S*H = 32768 sequential steps per
// (b,n) chain; 1024 chains. Bit-exactness with the fp32 sequential reference
// required -> add chain cannot be reassociated. Chain form (proven bit-exact
// R6..R19):   s' = prev ? x : fl(s + x);  prev' = s' > th
//
// R21: MEASUREMENT ROUND. R20's SGPR-x chain died on a constant-bus
// violation (v_cndmask always reads VCC -> SGPR src0 illegal), and on
// re-derivation the plan was negative-EV anyway: SMEM is unordered so any
// lgkmcnt wait drains ALL outstanding s_loads (lookahead collapses to ~80cyc
// vs ~250cyc SMEM latency), and the best case saved only ~0.1 instr/step.
//
// 4 of 13 rounds have produced no counters (2 infra, 1 asm crash, 1 compile
// error). This round banks the decisive unknown with ZERO new risk:
// lif_pass2 has NEVER appeared in top-5; R18's remainder 483.6-224 = 259.6us
// is an unknown split {pass2, fixed harness overhead}. Chain kernel is
// BYTE-IDENTICAL to R18 (proven 224us, absmax=0); pass2 is launched TWICE
// (idempotent: pure function of (x, ckpt), writes identical bytes), so
//     pass2_true = total - 483.6    (single-variable A/B vs R18)
// pass2 ~50  -> overhead ~210 -> R18 was ~20us from the structural floor
//               (chain-cadence floor 208 + pass2 + overhead): declare ceiling.
// pass2 ~200 -> overhead ~60 -> pass2 is the next target (~190us headroom).
//
// Chain: R18 verbatim. Cadence law (R16/R18/R19): lone wave retires ~5.1
// cyc/VALU-instr regardless of deps; chain = 3 instr/step in vcc-asm.
// Pass2: BYTE-IDENTICAL kernel to R8..R19 (proven absmax=0 eight times).

namespace {
constexpr int kB = 16;
constexpr int kS = 256;
constexpr int kH = 128;
constexpr int kN = 64;
constexpr int kT = kS * kH;                 // 32768
constexpr long kPerB = (long)kS * kN * kH;  // 2,097,152 per batch per tensor
// ws layout: ckpt_s | ckpt_m
constexpr size_t kWsS = (size_t)kB * kS * kN * sizeof(float);          // 1 MB
constexpr size_t kWsM = (size_t)kB * kS * sizeof(unsigned long long);  // 32 KB
}

typedef float v4f __attribute__((ext_vector_type(4)));
typedef unsigned long long u64;

// Opaque VGPR zero: defeats uniform-scalarization so wave-uniform-looking
// loads use the vector path (vmcnt, in-order) instead of SMEM s_loads
// (lgkmcnt, unordered -> full drains). Proven effective in R6.
__device__ __forceinline__ int opaque_vgpr_zero() {
  int z;
  asm volatile("v_mov_b32 %0, 0" : "=v"(z));
  return z;
}

// One chain step, exact ISA form, prev in vcc. Order matters: cndmask
// consumes OLD vcc, cmp then overwrites vcc for the next step.
#define LIF_STEP_ASM(XN)                              \
  "v_add_f32 %[t], %[s], %[" XN "]\n\t"               \
  "v_cndmask_b32 %[s], %[t], %[" XN "], vcc\n\t"      \
  "v_cmp_gt_f32 vcc, %[s], %[th]\n\t"

// 16 steps (4 quads) as a single asm block. pv: 0/1 int VGPR carrying prev
// across blocks; vcc live only inside the block (clobbered).
#define CHAIN16(Q0, Q1, Q2, Q3)                                             \
  {                                                                         \
    float tmp_;                                                             \
    asm volatile(                                                           \
        "v_cmp_ne_u32 vcc, 0, %[pv]\n\t"                                    \
        LIF_STEP_ASM("xa0") LIF_STEP_ASM("xa1")                             \
        LIF_STEP_ASM("xa2") LIF_STEP_ASM("xa3")                             \
        LIF_STEP_ASM("xb0") LIF_STEP_ASM("xb1")                             \
        LIF_STEP_ASM("xb2") LIF_STEP_ASM("xb3")                             \
        LIF_STEP_ASM("xc0") LIF_STEP_ASM("xc1")                             \
        LIF_STEP_ASM("xc2") LIF_STEP_ASM("xc3")                             \
        LIF_STEP_ASM("xd0") LIF_STEP_ASM("xd1")                             \
        LIF_STEP_ASM("xd2") LIF_STEP_ASM("xd3")                             \
        "v_cndmask_b32 %[pv], 0, 1, vcc\n\t"                                \
        : [s] "+v"(s), [pv] "+v"(pv), [t] "=&v"(tmp_)                       \
        : [xa0] "v"((Q0)[0]), [xa1] "v"((Q0)[1]),                           \
          [xa2] "v"((Q0)[2]), [xa3] "v"((Q0)[3]),                           \
          [xb0] "v"((Q1)[0]), [xb1] "v"((Q1)[1]),                           \
          [xb2] "v"((Q1)[2]), [xb3] "v"((Q1)[3]),                           \
          [xc0] "v"((Q2)[0]), [xc1] "v"((Q2)[1]),                           \
          [xc2] "v"((Q2)[2]), [xc3] "v"((Q2)[3]),                           \
          [xd0] "v"((Q3)[0]), [xd1] "v"((Q3)[1]),                           \
          [xd2] "v"((Q3)[2]), [xd3] "v"((Q3)[3]), [th] "v"(th)              \
        : "vcc");                                                           \
  }

// ---------------------------------------------------------------------------
// K1: the sequential chains, exact. block = batch, lane = neuron. x staged
// into LDS in 32KB quarters; 4-buffer static rotation + sched_barrier(0)
// fences (R16 structure); 16-step asm chain groups with prev in vcc.
// Checkpoints (entering state s + ballot(prev)) at every row.
// BYTE-IDENTICAL to R18 (proven 224us, absmax=0).
// ---------------------------------------------------------------------------
__global__ __launch_bounds__(64, 1) void lif_chain_kernel(
    const float* __restrict__ x, const float* __restrict__ thresh,
    const float* __restrict__ acc0, float* __restrict__ ckpt_s,
    u64* __restrict__ ckpt_m) {
  const int b = blockIdx.x;
  const int lane = threadIdx.x;
  const float th = thresh[lane];

  __shared__ v4f xs4[2048];  // 32 KB: one quarter (64 rows) of this batch

  const v4f* __restrict__ xg =
      (const v4f*)(x + (long)b * kT) + opaque_vgpr_zero();

  float s = acc0[b * kN + lane];
  int pv = 0;  // prev as 0/1 (false at t=0)

  float* __restrict__ cs = ckpt_s + (long)b * kS * kN + lane;
  u64* __restrict__ cm = ckpt_m + (long)b * kS;

#pragma unroll 1
  for (int q = 0; q < 4; ++q) {
    // ---- stage quarter q (proven pattern: 32 loads in flight, then 32
    // contiguous ds_writes; single wave -> DS in-order, no barrier needed)
    {
      const v4f* __restrict__ src = xg + (long)q * 2048 + lane;
      v4f tmp[32];
#pragma unroll
      for (int i = 0; i < 32; ++i) tmp[i] = src[i * 64];
#pragma unroll
      for (int i = 0; i < 32; ++i) xs4[i * 64 + lane] = tmp[i];
    }

    // ---- consume: 512 flat groups (64 rows x 8 groups of 16 steps).
    // Static 4-set rotation A,B,C,D: group k consumes set (k%4), group k
    // prefetches flat-group gq+2 into set ((k+2)%4).
    v4f A0, A1, A2, A3, B0, B1, B2, B3;
    v4f C0, C1, C2, C3, D0, D1, D2, D3;
    A0 = xs4[0]; A1 = xs4[1]; A2 = xs4[2]; A3 = xs4[3];  // group 0
    B0 = xs4[4]; B1 = xs4[5]; B2 = xs4[6]; B3 = xs4[7];  // group 1
    __builtin_amdgcn_sched_barrier(0);

#define LIF_GROUP(U0, U1, U2, U3, P0, P1, P2, P3, OFS)                  \
  {                                                                     \
    const int pf = (gq + (OFS) <= 511) ? (gq + (OFS)) : 511;            \
    P0 = xs4[4 * pf + 0];                                               \
    P1 = xs4[4 * pf + 1];                                               \
    P2 = xs4[4 * pf + 2];                                               \
    P3 = xs4[4 * pf + 3];                                               \
    __builtin_amdgcn_sched_barrier(0);                                  \
    CHAIN16(U0, U1, U2, U3)                                             \
    __builtin_amdgcn_sched_barrier(0);                                  \
  }

#pragma unroll 1
    for (int j = 0; j < 64; ++j) {
      const int r = q * 64 + j;
      // checkpoint: entering state
      cs[(long)r * kN] = s;
      {
        const u64 m = __ballot(pv != 0);
        if (lane == 0) cm[r] = m;
      }
      const int gq = j * 8;
      LIF_GROUP(A0, A1, A2, A3, C0, C1, C2, C3, 2)  // k=0: use A, pf->C
      LIF_GROUP(B0, B1, B2, B3, D0, D1, D2, D3, 3)  // k=1: use B, pf->D
      LIF_GROUP(C0, C1, C2, C3, A0, A1, A2, A3, 4)  // k=2: use C, pf->A
      LIF_GROUP(D0, D1, D2, D3, B0, B1, B2, B3, 5)  // k=3: use D, pf->B
      LIF_GROUP(A0, A1, A2, A3, C0, C1, C2, C3, 6)  // k=4
      LIF_GROUP(B0, B1, B2, B3, D0, D1, D2, D3, 7)  // k=5
      LIF_GROUP(C0, C1, C2, C3, A0, A1, A2, A3, 8)  // k=6: pf next row g0
      LIF_GROUP(D0, D1, D2, D3, B0, B1, B2, B3, 9)  // k=7: pf next row g1
    }
#undef LIF_GROUP
    // invariant: A,B hold next quarter's stale data; prologue reloads after
    // restaging. All ds_reads retired before the staging ds_writes of the
    // next quarter (DS pipe in-order per wave).
  }
}

// ---------------------------------------------------------------------------
// K2: replay + dense coalesced write (byte-identical to R8..R19 pass2,
// proven absmax = 0). One wave per (b,row); lane = n.
// ---------------------------------------------------------------------------
__global__ __launch_bounds__(64, 2) void lif_pass2_kernel(
    const float* __restrict__ x, const float* __restrict__ thresh,
    const float* __restrict__ ckpt_s, const u64* __restrict__ ckpt_m,
    float* __restrict__ out) {
  const int wid = blockIdx.x;
  const int b = wid >> 8;
  const int srow = wid & 255;
  const int lane = threadIdx.x;

  __shared__ float ov[kH / 2][kN + 1];  // 16.6 KB

  const v4f* __restrict__ xr4 =
      (const v4f*)(x + (long)b * kT + srow * kH) + opaque_vgpr_zero();

  v4f xb[32];
#pragma unroll
  for (int i = 0; i < 32; ++i) xb[i] = xr4[i];  // 32 loads in flight

  const float th = thresh[lane];
  float s = ckpt_s[((long)b * kS + srow) * kN + lane];
  bool prev = (ckpt_m[b * kS + srow] >> lane) & 1ULL;

  float* __restrict__ obase = out + (long)b * kPerB + (long)srow * (kN * kH);
  float* __restrict__ sbase = obase + (long)kB * kPerB;

#pragma unroll
  for (int half = 0; half < 2; ++half) {
#pragma unroll
    for (int hh = 0; hh < kH / 2; ++hh) {
      const int h = half * (kH / 2) + hh;
      const float xt = xb[h >> 2][h & 3];
      const float u = s + xt;
      s = prev ? xt : u;  // bit-identical replay
      prev = s > th;
      ov[hh][lane] = prev ? s : 0.0f;
    }
    const int q = lane & 15;
    const int nsub = lane >> 4;
    const int h0 = half * (kH / 2) + q * 4;
#pragma unroll
    for (int i = 0; i < 16; ++i) {
      const int n = i * 4 + nsub;
      v4f o, sp;
#pragma unroll
      for (int j = 0; j < 4; ++j) {
        const float v = ov[q * 4 + j][n];
        o[j] = v;
        sp[j] = v > 0.0f ? 1.0f : 0.0f;
      }
      *(v4f*)(obase + (long)n * kH + h0) = o;
      *(v4f*)(sbase + (long)n * kH + h0) = sp;
    }
  }
}

// ---------------------------------------------------------------------------
// Fallback (tiny ws): R4's passing fused kernel (unchanged).
// ---------------------------------------------------------------------------
__global__ __launch_bounds__(128) void lif_fused_kernel(
    const float* __restrict__ x, const float* __restrict__ thresh,
    const float* __restrict__ acc0, float* __restrict__ out) {
  const int bid = blockIdx.x;
  const int b = bid >> 2;
  const int ng = bid & 3;
  const int tid = threadIdx.x;
  const int wave = tid >> 6;
  const int lane = tid & 63;
  __shared__ float buf[2][kH][64];
  const float* __restrict__ xb = x + (long)b * kT;
  float* __restrict__ outs_g = out + (long)b * kPerB + (long)(ng * 16) * kH;
  float* __restrict__ spks_g = outs_g + (long)kB * kPerB;
  if (wave == 0) {
    const int n = lane & 15;
    const float th = thresh[ng * 16 + n];
    float s = acc0[b * kN + ng * 16 + n];
    bool prev = false;
    for (int r = 0; r < kS + 1; ++r) {
      if (r < kS) {
        float* __restrict__ bk = &buf[r & 1][0][lane];
        const float* __restrict__ xr = xb + r * kH;
#pragma unroll
        for (int k = 0; k < kH; ++k) {
          const float xt = xr[k];
          const float u = s + xt;
          s = prev ? xt : u;
          prev = s > th;
          bk[k * 64] = s;
        }
      }
      __syncthreads();
    }
  } else {
    const int n = lane >> 2;
    const int hg = lane & 3;
    const float th = thresh[ng * 16 + n];
    for (int r = 0; r < kS + 1; ++r) {
      if (r > 0) {
        const int rr = r - 1;
        const float(*bk)[64] = buf[rr & 1];
        float* __restrict__ orow = outs_g + (long)rr * (kN * kH) + n * kH;
        float* __restrict__ srow = spks_g + (long)rr * (kN * kH) + n * kH;
#pragma unroll
        for (int i = 0; i < 8; ++i) {
          const int hh = hg * 4 + i * 16;
          v4f ovv, sv;
#pragma unroll
          for (int j = 0; j < 4; ++j) {
            const float v = bk[hh + j][n];
            const bool sp = v > th;
            ovv[j] = sp ? v : 0.0f;
            sv[j] = sp ? 1.0f : 0.0f;
          }
          *(v4f*)(orow + hh) = ovv;
          *(v4f*)(srow + hh) = sv;
        }
      }
      __syncthreads();
    }
  }
}

// ---------------------------------------------------------------------------
extern "C" void kernel_launch(void* const* d_in, const int* in_sizes, int n_in,
                              void* d_out, int out_size, void* d_ws, size_t ws_size,
                              hipStream_t stream) {
  const float* inputs = (const float*)d_in[0];    // [B,S,H] fp32
  const float* threshes = (const float*)d_in[1];  // [N] fp32
  const float* acc0 = (const float*)d_in[2];      // [B,N] fp32
  float* out = (float*)d_out;

  if (ws_size >= kWsS + kWsM) {
    float* ckpt_s = (float*)d_ws;
    u64* ckpt_m = (u64*)((char*)d_ws + kWsS);
    lif_chain_kernel<<<kB, kN, 0, stream>>>(inputs, threshes, acc0, ckpt_s,
                                            ckpt_m);
    // MEASUREMENT: pass2 launched TWICE (idempotent — pure function of
    // (x, ckpt), writes identical bytes to the same locations).
    //   pass2_true = total − 483.6   (chain is byte-identical to R18)
    // Revert to a single launch next round once pass2's true cost is known.
    lif_pass2_kernel<<<kB * kS, kN, 0, stream>>>(inputs, threshes, ckpt_s,
                                                 ckpt_m, out);
    lif_pass2_kernel<<<kB * kS, kN, 0, stream>>>(inputs, threshes, ckpt_s,
                                                 ckpt_m, out);
  } else {
    lif_fused_kernel<<<kB * 4, 128, 0, stream>>>(inputs, threshes, acc0, out);
  }
}

// Round 15
// 483.988 us; speedup vs baseline: 1.4326x; 1.0743x over previous
//
#include <hip/hip_runtime.h>

// LIF scan: B=16, S=256, H=128, N=64. T = S*H = 32768 sequential steps per
// (b,n) chain; 1024 chains. Bit-exactness with the fp32 sequential reference
// required -> add chain cannot be reassociated. Chain form (proven bit-exact
// R6..R21):   s' = prev ? x : fl(s + x);  prev' = s' > th
//
// R22: TERMINAL CONFIG — R18's exact single-launch configuration (best
// measured: 483.6us), reverting R21's pass2 double-launch measurement
// artifact. The R21 measurement closed the accounting:
//   chain   224.0us  cadence-bound: lone wave retires ~4.9-5.1 cyc/VALU
//                    instr regardless of deps (R16/R18/R19 triplet); chain
//                    needs >=3 VALU/step (add, select, cmp — bit-exactness
//                    forbids reformulation) -> floor ~208-218us. We measure
//                    3.42 instr/step x 4.8 cyc = 16.4 cyc/step. AT the line.
//   pass2    36.4us  at the HBM write roofline (268MB output; 6.3 TB/s
//                    achievable = 42.6us; L2 buffering explains the rest).
//   harness ~223us   fixed across all 14 measured rounds (220-265us,
//                    independent of kernel count/structure).
//   total = 224 + 36 + 223 = 483 = R18's measured 483.6. Structural limit.
//
// Chain: R18 verbatim (vcc-asm 3-instr step, LDS quarters, 4-buffer
// rotation + sched_barrier(0) fences). Pass2: BYTE-IDENTICAL to R8..R21
// (proven absmax=0 nine times).

namespace {
constexpr int kB = 16;
constexpr int kS = 256;
constexpr int kH = 128;
constexpr int kN = 64;
constexpr int kT = kS * kH;                 // 32768
constexpr long kPerB = (long)kS * kN * kH;  // 2,097,152 per batch per tensor
// ws layout: ckpt_s | ckpt_m
constexpr size_t kWsS = (size_t)kB * kS * kN * sizeof(float);          // 1 MB
constexpr size_t kWsM = (size_t)kB * kS * sizeof(unsigned long long);  // 32 KB
}

typedef float v4f __attribute__((ext_vector_type(4)));
typedef unsigned long long u64;

// Opaque VGPR zero: defeats uniform-scalarization so wave-uniform-looking
// loads use the vector path (vmcnt, in-order) instead of SMEM s_loads
// (lgkmcnt, unordered -> full drains). Proven effective in R6.
__device__ __forceinline__ int opaque_vgpr_zero() {
  int z;
  asm volatile("v_mov_b32 %0, 0" : "=v"(z));
  return z;
}

// One chain step, exact ISA form, prev in vcc. Order matters: cndmask
// consumes OLD vcc, cmp then overwrites vcc for the next step.
#define LIF_STEP_ASM(XN)                              \
  "v_add_f32 %[t], %[s], %[" XN "]\n\t"               \
  "v_cndmask_b32 %[s], %[t], %[" XN "], vcc\n\t"      \
  "v_cmp_gt_f32 vcc, %[s], %[th]\n\t"

// 16 steps (4 quads) as a single asm block. pv: 0/1 int VGPR carrying prev
// across blocks; vcc live only inside the block (clobbered).
#define CHAIN16(Q0, Q1, Q2, Q3)                                             \
  {                                                                         \
    float tmp_;                                                             \
    asm volatile(                                                           \
        "v_cmp_ne_u32 vcc, 0, %[pv]\n\t"                                    \
        LIF_STEP_ASM("xa0") LIF_STEP_ASM("xa1")                             \
        LIF_STEP_ASM("xa2") LIF_STEP_ASM("xa3")                             \
        LIF_STEP_ASM("xb0") LIF_STEP_ASM("xb1")                             \
        LIF_STEP_ASM("xb2") LIF_STEP_ASM("xb3")                             \
        LIF_STEP_ASM("xc0") LIF_STEP_ASM("xc1")                             \
        LIF_STEP_ASM("xc2") LIF_STEP_ASM("xc3")                             \
        LIF_STEP_ASM("xd0") LIF_STEP_ASM("xd1")                             \
        LIF_STEP_ASM("xd2") LIF_STEP_ASM("xd3")                             \
        "v_cndmask_b32 %[pv], 0, 1, vcc\n\t"                                \
        : [s] "+v"(s), [pv] "+v"(pv), [t] "=&v"(tmp_)                       \
        : [xa0] "v"((Q0)[0]), [xa1] "v"((Q0)[1]),                           \
          [xa2] "v"((Q0)[2]), [xa3] "v"((Q0)[3]),                           \
          [xb0] "v"((Q1)[0]), [xb1] "v"((Q1)[1]),                           \
          [xb2] "v"((Q1)[2]), [xb3] "v"((Q1)[3]),                           \
          [xc0] "v"((Q2)[0]), [xc1] "v"((Q2)[1]),                           \
          [xc2] "v"((Q2)[2]), [xc3] "v"((Q2)[3]),                           \
          [xd0] "v"((Q3)[0]), [xd1] "v"((Q3)[1]),                           \
          [xd2] "v"((Q3)[2]), [xd3] "v"((Q3)[3]), [th] "v"(th)              \
        : "vcc");                                                           \
  }

// ---------------------------------------------------------------------------
// K1: the sequential chains, exact. block = batch, lane = neuron. x staged
// into LDS in 32KB quarters; 4-buffer static rotation + sched_barrier(0)
// fences; 16-step asm chain groups with prev in vcc. Checkpoints (entering
// state s + ballot(prev)) at every row. BYTE-IDENTICAL to R18 (224us).
// ---------------------------------------------------------------------------
__global__ __launch_bounds__(64, 1) void lif_chain_kernel(
    const float* __restrict__ x, const float* __restrict__ thresh,
    const float* __restrict__ acc0, float* __restrict__ ckpt_s,
    u64* __restrict__ ckpt_m) {
  const int b = blockIdx.x;
  const int lane = threadIdx.x;
  const float th = thresh[lane];

  __shared__ v4f xs4[2048];  // 32 KB: one quarter (64 rows) of this batch

  const v4f* __restrict__ xg =
      (const v4f*)(x + (long)b * kT) + opaque_vgpr_zero();

  float s = acc0[b * kN + lane];
  int pv = 0;  // prev as 0/1 (false at t=0)

  float* __restrict__ cs = ckpt_s + (long)b * kS * kN + lane;
  u64* __restrict__ cm = ckpt_m + (long)b * kS;

#pragma unroll 1
  for (int q = 0; q < 4; ++q) {
    // ---- stage quarter q (proven pattern: 32 loads in flight, then 32
    // contiguous ds_writes; single wave -> DS in-order, no barrier needed)
    {
      const v4f* __restrict__ src = xg + (long)q * 2048 + lane;
      v4f tmp[32];
#pragma unroll
      for (int i = 0; i < 32; ++i) tmp[i] = src[i * 64];
#pragma unroll
      for (int i = 0; i < 32; ++i) xs4[i * 64 + lane] = tmp[i];
    }

    // ---- consume: 512 flat groups (64 rows x 8 groups of 16 steps).
    // Static 4-set rotation A,B,C,D: group k consumes set (k%4), group k
    // prefetches flat-group gq+2 into set ((k+2)%4).
    v4f A0, A1, A2, A3, B0, B1, B2, B3;
    v4f C0, C1, C2, C3, D0, D1, D2, D3;
    A0 = xs4[0]; A1 = xs4[1]; A2 = xs4[2]; A3 = xs4[3];  // group 0
    B0 = xs4[4]; B1 = xs4[5]; B2 = xs4[6]; B3 = xs4[7];  // group 1
    __builtin_amdgcn_sched_barrier(0);

#define LIF_GROUP(U0, U1, U2, U3, P0, P1, P2, P3, OFS)                  \
  {                                                                     \
    const int pf = (gq + (OFS) <= 511) ? (gq + (OFS)) : 511;            \
    P0 = xs4[4 * pf + 0];                                               \
    P1 = xs4[4 * pf + 1];                                               \
    P2 = xs4[4 * pf + 2];                                               \
    P3 = xs4[4 * pf + 3];                                               \
    __builtin_amdgcn_sched_barrier(0);                                  \
    CHAIN16(U0, U1, U2, U3)                                             \
    __builtin_amdgcn_sched_barrier(0);                                  \
  }

#pragma unroll 1
    for (int j = 0; j < 64; ++j) {
      const int r = q * 64 + j;
      // checkpoint: entering state
      cs[(long)r * kN] = s;
      {
        const u64 m = __ballot(pv != 0);
        if (lane == 0) cm[r] = m;
      }
      const int gq = j * 8;
      LIF_GROUP(A0, A1, A2, A3, C0, C1, C2, C3, 2)  // k=0: use A, pf->C
      LIF_GROUP(B0, B1, B2, B3, D0, D1, D2, D3, 3)  // k=1: use B, pf->D
      LIF_GROUP(C0, C1, C2, C3, A0, A1, A2, A3, 4)  // k=2: use C, pf->A
      LIF_GROUP(D0, D1, D2, D3, B0, B1, B2, B3, 5)  // k=3: use D, pf->B
      LIF_GROUP(A0, A1, A2, A3, C0, C1, C2, C3, 6)  // k=4
      LIF_GROUP(B0, B1, B2, B3, D0, D1, D2, D3, 7)  // k=5
      LIF_GROUP(C0, C1, C2, C3, A0, A1, A2, A3, 8)  // k=6: pf next row g0
      LIF_GROUP(D0, D1, D2, D3, B0, B1, B2, B3, 9)  // k=7: pf next row g1
    }
#undef LIF_GROUP
    // invariant: A,B hold next quarter's stale data; prologue reloads after
    // restaging. All ds_reads retired before the staging ds_writes of the
    // next quarter (DS pipe in-order per wave).
  }
}

// ---------------------------------------------------------------------------
// K2: replay + dense coalesced write (byte-identical to R8..R21 pass2,
// proven absmax = 0; measured 36.4us = HBM write roofline). One wave per
// (b,row); lane = n.
// ---------------------------------------------------------------------------
__global__ __launch_bounds__(64, 2) void lif_pass2_kernel(
    const float* __restrict__ x, const float* __restrict__ thresh,
    const float* __restrict__ ckpt_s, const u64* __restrict__ ckpt_m,
    float* __restrict__ out) {
  const int wid = blockIdx.x;
  const int b = wid >> 8;
  const int srow = wid & 255;
  const int lane = threadIdx.x;

  __shared__ float ov[kH / 2][kN + 1];  // 16.6 KB

  const v4f* __restrict__ xr4 =
      (const v4f*)(x + (long)b * kT + srow * kH) + opaque_vgpr_zero();

  v4f xb[32];
#pragma unroll
  for (int i = 0; i < 32; ++i) xb[i] = xr4[i];  // 32 loads in flight

  const float th = thresh[lane];
  float s = ckpt_s[((long)b * kS + srow) * kN + lane];
  bool prev = (ckpt_m[b * kS + srow] >> lane) & 1ULL;

  float* __restrict__ obase = out + (long)b * kPerB + (long)srow * (kN * kH);
  float* __restrict__ sbase = obase + (long)kB * kPerB;

#pragma unroll
  for (int half = 0; half < 2; ++half) {
#pragma unroll
    for (int hh = 0; hh < kH / 2; ++hh) {
      const int h = half * (kH / 2) + hh;
      const float xt = xb[h >> 2][h & 3];
      const float u = s + xt;
      s = prev ? xt : u;  // bit-identical replay
      prev = s > th;
      ov[hh][lane] = prev ? s : 0.0f;
    }
    const int q = lane & 15;
    const int nsub = lane >> 4;
    const int h0 = half * (kH / 2) + q * 4;
#pragma unroll
    for (int i = 0; i < 16; ++i) {
      const int n = i * 4 + nsub;
      v4f o, sp;
#pragma unroll
      for (int j = 0; j < 4; ++j) {
        const float v = ov[q * 4 + j][n];
        o[j] = v;
        sp[j] = v > 0.0f ? 1.0f : 0.0f;
      }
      *(v4f*)(obase + (long)n * kH + h0) = o;
      *(v4f*)(sbase + (long)n * kH + h0) = sp;
    }
  }
}

// ---------------------------------------------------------------------------
// Fallback (tiny ws): R4's passing fused kernel (unchanged).
// ---------------------------------------------------------------------------
__global__ __launch_bounds__(128) void lif_fused_kernel(
    const float* __restrict__ x, const float* __restrict__ thresh,
    const float* __restrict__ acc0, float* __restrict__ out) {
  const int bid = blockIdx.x;
  const int b = bid >> 2;
  const int ng = bid & 3;
  const int tid = threadIdx.x;
  const int wave = tid >> 6;
  const int lane = tid & 63;
  __shared__ float buf[2][kH][64];
  const float* __restrict__ xb = x + (long)b * kT;
  float* __restrict__ outs_g = out + (long)b * kPerB + (long)(ng * 16) * kH;
  float* __restrict__ spks_g = outs_g + (long)kB * kPerB;
  if (wave == 0) {
    const int n = lane & 15;
    const float th = thresh[ng * 16 + n];
    float s = acc0[b * kN + ng * 16 + n];
    bool prev = false;
    for (int r = 0; r < kS + 1; ++r) {
      if (r < kS) {
        float* __restrict__ bk = &buf[r & 1][0][lane];
        const float* __restrict__ xr = xb + r * kH;
#pragma unroll
        for (int k = 0; k < kH; ++k) {
          const float xt = xr[k];
          const float u = s + xt;
          s = prev ? xt : u;
          prev = s > th;
          bk[k * 64] = s;
        }
      }
      __syncthreads();
    }
  } else {
    const int n = lane >> 2;
    const int hg = lane & 3;
    const float th = thresh[ng * 16 + n];
    for (int r = 0; r < kS + 1; ++r) {
      if (r > 0) {
        const int rr = r - 1;
        const float(*bk)[64] = buf[rr & 1];
        float* __restrict__ orow = outs_g + (long)rr * (kN * kH) + n * kH;
        float* __restrict__ srow = spks_g + (long)rr * (kN * kH) + n * kH;
#pragma unroll
        for (int i = 0; i < 8; ++i) {
          const int hh = hg * 4 + i * 16;
          v4f ovv, sv;
#pragma unroll
          for (int j = 0; j < 4; ++j) {
            const float v = bk[hh + j][n];
            const bool sp = v > th;
            ovv[j] = sp ? v : 0.0f;
            sv[j] = sp ? 1.0f : 0.0f;
          }
          *(v4f*)(orow + hh) = ovv;
          *(v4f*)(srow + hh) = sv;
        }
      }
      __syncthreads();
    }
  }
}

// ---------------------------------------------------------------------------
extern "C" void kernel_launch(void* const* d_in, const int* in_sizes, int n_in,
                              void* d_out, int out_size, void* d_ws, size_t ws_size,
                              hipStream_t stream) {
  const float* inputs = (const float*)d_in[0];    // [B,S,H] fp32
  const float* threshes = (const float*)d_in[1];  // [N] fp32
  const float* acc0 = (const float*)d_in[2];      // [B,N] fp32
  float* out = (float*)d_out;

  if (ws_size >= kWsS + kWsM) {
    float* ckpt_s = (float*)d_ws;
    u64* ckpt_m = (u64*)((char*)d_ws + kWsS);
    lif_chain_kernel<<<kB, kN, 0, stream>>>(inputs, threshes, acc0, ckpt_s,
                                            ckpt_m);
    lif_pass2_kernel<<<kB * kS, kN, 0, stream>>>(inputs, threshes, ckpt_s,
                                                 ckpt_m, out);
  } else {
    lif_fused_kernel<<<kB * 4, 128, 0, stream>>>(inputs, threshes, acc0, out);
  }
}